// Round 20
// baseline (380.276 us; speedup 1.0000x reference)
//
#include <hip/hip_runtime.h>

constexpr int HH   = 4;    // heads
constexpr int DINC = 128;  // input feature dim
constexpr int OUTC = 128;  // output feature dim (H*D)
constexpr int NCMB = 272;  // combined B cols: 128 Ws | 128 Wd | 4 vs | 4 vd | 8 pad
constexpr int SCAN_B = 64;

typedef __attribute__((ext_vector_type(4))) float f32x4;
typedef __attribute__((ext_vector_type(2))) float f32x2;
typedef __attribute__((ext_vector_type(8))) short bf16x8;

__device__ __forceinline__ float leaky(float x){ return x >= 0.f ? x : 0.2f*x; }
__device__ __forceinline__ unsigned short f2bf(float f){ unsigned u=__float_as_uint(f); return (unsigned short)((u + 0x7FFFu + ((u>>16)&1u))>>16); }
__device__ __forceinline__ float bf2f(unsigned s){ return __uint_as_float(s<<16); }

// ---------------- K0: prep — element-parallel (+ deg zeroing) ----------------
__global__ __launch_bounds__(256) void prep_kernel(
    const float* __restrict__ Ws, const float* __restrict__ Wd, const float* __restrict__ We,
    const float* __restrict__ as_, const float* __restrict__ ad_, const float* __restrict__ ae_,
    unsigned short* __restrict__ wcmb, unsigned short* __restrict__ webft,
    unsigned short* __restrict__ veb, int* __restrict__ deg, int N)
{
  int tid = blockIdx.x*256 + threadIdx.x;
  int stride = gridDim.x*256;
  for (int idx = tid; idx < NCMB*DINC; idx += stride) {
    int j = idx >> 7, k = idx & 127;
    float w;
    if      (j < 128) w = Ws[j*DINC + k];
    else if (j < 256) w = Wd[(j-128)*DINC + k];
    else if (j < 260) { int h=j-256; float s=0.f; for(int d=0;d<32;++d) s += as_[h*32+d]*Ws[(h*32+d)*DINC+k]; w=s; }
    else if (j < 264) { int h=j-260; float s=0.f; for(int d=0;d<32;++d) s += ad_[h*32+d]*Wd[(h*32+d)*DINC+k]; w=s; }
    else w = 0.f;
    wcmb[idx] = f2bf(w);
  }
  for (int idx = tid; idx < 16*DINC; idx += stride) {   // veb[16][128]: 4 real head rows
    int h = idx >> 7, k = idx & 127;
    float w = 0.f;
    if (h < HH) { float s=0.f; for(int d=0;d<32;++d) s += ae_[h*32+d]*We[(h*32+d)*DINC+k]; w=s; }
    veb[idx] = f2bf(w);
  }
  for (int idx = tid; idx < DINC*OUTC; idx += stride)   // webft[j][k] = We row-major bf16
    webft[idx] = f2bf(We[idx]);
  for (int idx = tid; idx < N; idx += stride) deg[idx] = 0;
}

// ---------------- K1: MFMA node GEMM C[32,272] = X @ [Ws|Wd|vs|vd]^T + fused histogram ----------------
__global__ __launch_bounds__(256) void node_mfma(
    const float* __restrict__ X, const unsigned short* __restrict__ wcmb,
    const int* __restrict__ dst, int* __restrict__ deg,
    unsigned short* __restrict__ hsrcbf, unsigned short* __restrict__ hdstbf,
    float* __restrict__ esrc, float* __restrict__ edst, int N, int E)
{
  int t = threadIdx.x;
  for (long e = (long)blockIdx.x*256 + t; e < E; e += (long)gridDim.x*256)
    atomicAdd(deg + dst[e], 1);

  int lane = t & 63, wv = t >> 6;
  int r16 = lane & 15, g = lane >> 4;
  int n0 = blockIdx.x * 32;
  int ntS = (wv*17) >> 2, ntE = ((wv+1)*17) >> 2;

  #pragma unroll
  for (int mt = 0; mt < 2; ++mt) {
    int arow = n0 + mt*16 + r16; if (arow >= N) arow = N-1;
    bf16x8 a[4];
    #pragma unroll
    for (int kc = 0; kc < 4; ++kc) {
      const float* ap = X + (long)arow*DINC + kc*32 + g*8;
      f32x4 x0 = *(const f32x4*)ap;
      f32x4 x1 = *(const f32x4*)(ap + 4);
      bf16x8 af;
      af[0]=f2bf(x0[0]); af[1]=f2bf(x0[1]); af[2]=f2bf(x0[2]); af[3]=f2bf(x0[3]);
      af[4]=f2bf(x1[0]); af[5]=f2bf(x1[1]); af[6]=f2bf(x1[2]); af[7]=f2bf(x1[3]);
      a[kc] = af;
    }
    for (int nt = ntS; nt < ntE; ++nt) {
      f32x4 acc = (f32x4){0,0,0,0};
      #pragma unroll
      for (int kc = 0; kc < 4; ++kc) {
        bf16x8 bf = *(const bf16x8*)(wcmb + (nt*16 + r16)*DINC + kc*32 + g*8);
        acc = __builtin_amdgcn_mfma_f32_16x16x32_bf16(a[kc], bf, acc, 0, 0, 0);
      }
      int j = nt*16 + r16;   // D: col = lane&15, row = g*4 + r
      #pragma unroll
      for (int r = 0; r < 4; ++r) {
        int n = n0 + mt*16 + g*4 + r;
        if (n >= N) continue;
        float v = acc[r];
        if      (j < 128) hsrcbf[(long)n*OUTC + j] = f2bf(v);
        else if (j < 256) hdstbf[(long)n*OUTC + (j-128)] = f2bf(v);
        else if (j < 260) esrc[(long)n*HH + (j-256)] = v;
        else if (j < 264) edst[(long)n*HH + (j-260)] = v;
      }
    }
  }
}

// ---------------- scan: 3-phase parallel exclusive scan of deg ----------------
__global__ __launch_bounds__(256) void scan1(const int* __restrict__ deg, int* __restrict__ bsum, int N)
{
  __shared__ int sh[256];
  int t = threadIdx.x, blk = blockIdx.x;
  int R = (N + SCAN_B*256 - 1) / (SCAN_B*256);
  int base = (blk*256 + t)*R;
  int s = 0;
  for (int i = 0; i < R; ++i) { int idx = base + i; if (idx < N) s += deg[idx]; }
  sh[t] = s; __syncthreads();
  for (int d = 128; d > 0; d >>= 1) { if (t < d) sh[t] += sh[t+d]; __syncthreads(); }
  if (t == 0) bsum[blk] = sh[0];
}

__global__ __launch_bounds__(64) void scan2(const int* __restrict__ bsum, int* __restrict__ bpre,
                                            int* __restrict__ off, int N)
{
  if (threadIdx.x == 0) {
    int r = 0;
    for (int b = 0; b < SCAN_B; ++b) { bpre[b] = r; r += bsum[b]; }
    off[N] = r;
  }
}

__global__ __launch_bounds__(256) void scan3(const int* __restrict__ deg, const int* __restrict__ bpre,
                                             int* __restrict__ off, int* __restrict__ cursor, int N)
{
  __shared__ int sh[256];
  int t = threadIdx.x, blk = blockIdx.x;
  int R = (N + SCAN_B*256 - 1) / (SCAN_B*256);
  int base = (blk*256 + t)*R;
  int s = 0;
  for (int i = 0; i < R; ++i) { int idx = base + i; if (idx < N) s += deg[idx]; }
  sh[t] = s; __syncthreads();
  for (int d = 1; d < 256; d <<= 1) {
    int v = (t >= d) ? sh[t-d] : 0;
    __syncthreads();
    sh[t] += v;
    __syncthreads();
  }
  int r = bpre[blk] + sh[t] - s;
  for (int i = 0; i < R; ++i) {
    int idx = base + i;
    if (idx < N) { off[idx] = r; cursor[idx] = r; r += deg[idx]; }
  }
}

// ---------------- scatter: 8B CSR records {src, eid} ----------------
__global__ __launch_bounds__(256) void scatter_kernel(
    const int* __restrict__ src, const int* __restrict__ dst,
    int* __restrict__ cursor, unsigned long long* __restrict__ csr, int E)
{
  int e = blockIdx.x*256 + threadIdx.x;
  if (e >= E) return;
  int p = atomicAdd(cursor + dst[e], 1);
  csr[p] = ((unsigned long long)(unsigned)src[e] << 32) | (unsigned)e;
}

// ---------------- K4: FUSED per-node aggregation — R18 + register-shfl src broadcast ----------------
// Wave = node. Phase A per 16-edge chunk: csr -> (Xe gather -> A-frags -> LDS + logit MFMA
// -> nu2 -> S2) AND (esrc own-s_ load -> n1 -> S1L, denominator in-register).
// Phase B: s_ comes from __shfl of the Phase-A register (no LDS hop); one hu gather + LDS reads.
__global__ __launch_bounds__(256) void aggregate_fused(
    const float* __restrict__ Xe, const unsigned short* __restrict__ veb,
    const unsigned* __restrict__ hsrcbfu, const unsigned* __restrict__ hdstbfu,
    const float* __restrict__ esrc, const float* __restrict__ edst,
    const unsigned long long* __restrict__ csr, const int* __restrict__ off,
    unsigned* __restrict__ Ybfu, float* __restrict__ out, int N)
{
  struct WaveLds {
    unsigned short XeL[16][DINC+8];   // bf16 Xe rows of current chunk (pad 8)
    float S2[16][HH];                 // nu2 per (edge-in-chunk, head)
    float S1L[16][HH];                // n1 per (edge-in-chunk, head)
  };
  __shared__ WaveLds L[4];

  int t = threadIdx.x, wid = t >> 6, lane = t & 63;
  int r16 = lane & 15, g = lane >> 4;
  int n = blockIdx.x*4 + wid;
  bool valid = (n < N);
  int beg = 0, end = 0;
  if (valid) { beg = off[n]; end = off[n+1]; }
  int hl = g;                  // head owned by this lane (cols 2*lane)
  int j0 = 2*lane;
  f32x4 edh4 = valid ? *(const f32x4*)(edst + (long)n*HH) : (f32x4){0,0,0,0};
  float edh  = edh4[hl];       // head g — used for n1 (lane's own head)
  float edhr = edh4[r16 & 3];  // used for nu2 at logit lanes

  bf16x8 vebf[4];
  #pragma unroll
  for (int kc = 0; kc < 4; ++kc)
    vebf[kc] = *(const bf16x8*)(veb + r16*DINC + kc*32 + g*8);

  f32x2 acc = {0.f,0.f};
  f32x2 Y0={0,0}, Y1={0,0}, Y2={0,0}, Y3={0,0};
  float s1a = 0.f;             // per-lane partial of head-g denominator (edge r16 slice)
  f32x4 s2v = {0,0,0,0};

  for (int p0 = beg; p0 < end; p0 += 16) {
    int cnt = min(16, end - p0);
    // --- Phase A: csr entry, all gathers issued together ---
    long pr = (long)p0 + r16; if (pr >= end) pr = end - 1;
    unsigned long long pk = csr[pr];
    int s_ = (int)(pk >> 32);
    long eid = (long)(unsigned)pk;

    // n1 for (edge r16, head g): own-s_ load, issued before Xe loads
    float esl = esrc[(long)s_*HH + g];

    f32x4 accq = (f32x4){0,0,0,0};
    #pragma unroll
    for (int kc = 0; kc < 4; ++kc) {
      const float* ap = Xe + eid*DINC + kc*32 + g*8;
      f32x4 x0 = *(const f32x4*)ap;
      f32x4 x1 = *(const f32x4*)(ap + 4);
      bf16x8 af;
      af[0]=f2bf(x0[0]); af[1]=f2bf(x0[1]); af[2]=f2bf(x0[2]); af[3]=f2bf(x0[3]);
      af[4]=f2bf(x1[0]); af[5]=f2bf(x1[1]); af[6]=f2bf(x1[2]); af[7]=f2bf(x1[3]);
      *(bf16x8*)&L[wid].XeL[r16][kc*32 + g*8] = af;
      accq = __builtin_amdgcn_mfma_f32_16x16x32_bf16(af, vebf[kc], accq, 0, 0, 0);
    }

    float n1A = ((p0 + r16) < end) ? __expf(leaky(esl + edh)) : 0.f;
    L[wid].S1L[r16][g] = n1A;
    s1a += n1A;

    if (r16 < HH) {            // logits D: col r16 = head, row g*4+r = edge-in-chunk
      #pragma unroll
      for (int r = 0; r < 4; ++r) {
        float n2 = ((p0 + g*4 + r) < end) ? __expf(leaky(accq[r] + edhr)) : 0.f;
        L[wid].S2[g*4 + r][r16] = n2;
      }
    }
    asm volatile("s_waitcnt lgkmcnt(0)" ::: "memory");   // wave-local: drain LDS writes
    __builtin_amdgcn_sched_barrier(0);

    // --- Phase B: src id via register shfl; one hu gather per edge + LDS reads ---
    for (int i = 0; i < cnt; ++i) {
      int s2_ = __shfl(s_, i, 64);                       // lane i holds row i's src id
      f32x4 nu2 = *(const f32x4*)L[wid].S2[i];
      float n1 = L[wid].S1L[i][hl];
      unsigned xu = *(const unsigned*)&L[wid].XeL[i][j0];
      unsigned hu = hsrcbfu[(long)s2_*64 + lane];
      f32x2 xe; xe[0] = bf2f(xu & 0xffffu); xe[1] = bf2f(xu >> 16);
      f32x2 hs; hs[0] = bf2f(hu & 0xffffu); hs[1] = bf2f(hu >> 16);
      s2v += nu2;
      acc += n1*hs;
      Y0 += nu2[0]*xe; Y1 += nu2[1]*xe; Y2 += nu2[2]*xe; Y3 += nu2[3]*xe;
    }
    asm volatile("" ::: "memory");   // keep next chunk's LDS writes after these reads
  }

  // head-g denominator: reduce s1a over the 16-lane r16 group (g preserved)
  s1a += __shfl_xor(s1a, 1, 64); s1a += __shfl_xor(s1a, 2, 64);
  s1a += __shfl_xor(s1a, 4, 64); s1a += __shfl_xor(s1a, 8, 64);
  float is1h = (s1a != 0.f) ? 1.f / s1a : 0.f;
  f32x4 is2;
  #pragma unroll
  for (int h=0; h<HH; ++h) is2[h] = (s2v[h] != 0.f) ? 1.f / s2v[h] : 0.f;
  acc *= is1h;
  Y0 *= is2[0]; Y1 *= is2[1]; Y2 *= is2[2]; Y3 *= is2[3];

  if (valid) {
    // Ybf[n][h][k]: lane packs cols (2*lane, 2*lane+1) of each head -> 4 coalesced 256B stores
    unsigned* yp = Ybfu + (long)n*256;
    yp[0*64 + lane] = (unsigned)f2bf(Y0[0]) | ((unsigned)f2bf(Y0[1]) << 16);
    yp[1*64 + lane] = (unsigned)f2bf(Y1[0]) | ((unsigned)f2bf(Y1[1]) << 16);
    yp[2*64 + lane] = (unsigned)f2bf(Y2[0]) | ((unsigned)f2bf(Y2[1]) << 16);
    yp[3*64 + lane] = (unsigned)f2bf(Y3[0]) | ((unsigned)f2bf(Y3[1]) << 16);
    unsigned bu = hdstbfu[(long)n*64 + lane];
    out[(long)n*OUTC + j0]     = bf2f(bu & 0xffffu) + acc[0];
    out[(long)n*OUTC + j0 + 1] = bf2f(bu >> 16)     + acc[1];
  }
}

// ---------------- K5: batched projection out[n,j] += Y[n, j>>5, :] . We[j, :]  (MFMA) ----------------
__global__ __launch_bounds__(256) void proj_mfma(
    const unsigned short* __restrict__ Ybf,   // [N][4][128] bf16
    const unsigned short* __restrict__ webft, // [128][128] bf16, We row-major
    float* __restrict__ out, int N)
{
  int t = threadIdx.x, lane = t & 63, wv = t >> 6;
  int r16 = lane & 15, g = lane >> 4;
  int n0 = blockIdx.x * 32;
  int h = wv;                               // head handled by this wave

  #pragma unroll
  for (int mt = 0; mt < 2; ++mt) {
    int arow = n0 + mt*16 + r16; if (arow >= N) arow = N-1;
    bf16x8 a[4];
    #pragma unroll
    for (int kc = 0; kc < 4; ++kc)
      a[kc] = *(const bf16x8*)(Ybf + ((long)arow*4 + h)*DINC + kc*32 + g*8);
    #pragma unroll
    for (int ts = 0; ts < 2; ++ts) {
      int nt = wv*2 + ts;
      f32x4 acc = (f32x4){0,0,0,0};
      #pragma unroll
      for (int kc = 0; kc < 4; ++kc) {
        bf16x8 bw = *(const bf16x8*)(webft + (long)(nt*16 + r16)*DINC + kc*32 + g*8);
        acc = __builtin_amdgcn_mfma_f32_16x16x32_bf16(a[kc], bw, acc, 0, 0, 0);
      }
      int j = nt*16 + r16;   // D: col = lane&15 -> j; row = g*4 + r -> node
      #pragma unroll
      for (int r = 0; r < 4; ++r) {
        int n = n0 + mt*16 + g*4 + r;
        if (n < N) out[(long)n*OUTC + j] += acc[r];
      }
    }
  }
}

extern "C" void kernel_launch(void* const* d_in, const int* in_sizes, int n_in,
                              void* d_out, int out_size, void* d_ws, size_t ws_size,
                              hipStream_t stream) {
  const float* X   = (const float*)d_in[0];
  const float* Xe  = (const float*)d_in[1];
  const float* Ws  = (const float*)d_in[2];
  const float* Wd  = (const float*)d_in[3];
  const float* We  = (const float*)d_in[4];
  const float* as_ = (const float*)d_in[5];
  const float* ad_ = (const float*)d_in[6];
  const float* ae_ = (const float*)d_in[7];
  const int* src   = (const int*)d_in[8];
  const int* dst   = (const int*)d_in[9];
  int N = in_sizes[0] / DINC;
  int E = in_sizes[8];
  float* out = (float*)d_out;

  char* ws = (char*)d_ws;
  auto align256 = [](size_t x){ return (x + 255) & ~(size_t)255; };
  size_t o_hsrc  = 0;                                        // bf16 [N][128]
  size_t o_hdst  = align256(o_hsrc + (size_t)N*OUTC*2);      // bf16 [N][128]
  size_t o_ybf   = align256(o_hdst + (size_t)N*OUTC*2);      // bf16 [N][4][128]
  size_t o_esrc  = align256(o_ybf  + (size_t)N*HH*DINC*2);
  size_t o_edst  = align256(o_esrc + (size_t)N*HH*4);
  size_t o_csr   = align256(o_edst + (size_t)N*HH*4);        // u64 [E], CSR order
  size_t o_wcmb  = align256(o_csr  + (size_t)E*8);
  size_t o_webft = align256(o_wcmb + (size_t)NCMB*DINC*2);
  size_t o_veb   = align256(o_webft+ (size_t)DINC*OUTC*2);
  size_t o_deg   = align256(o_veb  + (size_t)16*DINC*2);
  size_t o_off   = align256(o_deg  + (size_t)N*4);
  size_t o_cur   = align256(o_off  + (size_t)(N+4)*4);
  size_t o_bsum  = align256(o_cur  + (size_t)N*4);
  size_t o_bpre  = align256(o_bsum + (size_t)SCAN_B*4);

  unsigned short* hsrcbf = (unsigned short*)(ws + o_hsrc);
  unsigned short* hdstbf = (unsigned short*)(ws + o_hdst);
  unsigned short* ybf    = (unsigned short*)(ws + o_ybf);
  float* esrc  = (float*)(ws + o_esrc);
  float* edstp = (float*)(ws + o_edst);
  unsigned long long* csr = (unsigned long long*)(ws + o_csr);
  unsigned short* wcmb  = (unsigned short*)(ws + o_wcmb);
  unsigned short* webft = (unsigned short*)(ws + o_webft);
  unsigned short* veb   = (unsigned short*)(ws + o_veb);
  int* deg     = (int*)(ws + o_deg);
  int* off     = (int*)(ws + o_off);
  int* cursor  = (int*)(ws + o_cur);
  int* bsum    = (int*)(ws + o_bsum);
  int* bpre    = (int*)(ws + o_bpre);

  prep_kernel<<<32, 256, 0, stream>>>(Ws, Wd, We, as_, ad_, ae_, wcmb, webft, veb, deg, N);
  node_mfma<<<(N + 31)/32, 256, 0, stream>>>(X, wcmb, dst, deg, hsrcbf, hdstbf, esrc, edstp, N, E);
  scan1<<<SCAN_B, 256, 0, stream>>>(deg, bsum, N);
  scan2<<<1, 64, 0, stream>>>(bsum, bpre, off, N);
  scan3<<<SCAN_B, 256, 0, stream>>>(deg, bpre, off, cursor, N);
  scatter_kernel<<<(E + 255)/256, 256, 0, stream>>>(src, dst, cursor, csr, E);
  aggregate_fused<<<(N + 3)/4, 256, 0, stream>>>(Xe, veb, (const unsigned*)hsrcbf, (const unsigned*)hdstbf,
                                                 esrc, edstp, csr, off, (unsigned*)ybf, out, N);
  proj_mfma<<<(N + 31)/32, 256, 0, stream>>>(ybf, webft, out, N);
}

// Round 22
// 323.244 us; speedup vs baseline: 1.1764x; 1.1764x over previous
//
#include <hip/hip_runtime.h>

constexpr int HH   = 4;    // heads
constexpr int DINC = 128;  // input feature dim
constexpr int OUTC = 128;  // output feature dim (H*D)
constexpr int NCMB = 272;  // combined B cols: 128 Ws | 128 Wd | 4 vs | 4 vd | 8 pad
constexpr int SCAN_B = 64;

typedef __attribute__((ext_vector_type(4))) float f32x4;
typedef __attribute__((ext_vector_type(2))) float f32x2;
typedef __attribute__((ext_vector_type(8))) short bf16x8;

__device__ __forceinline__ float leaky(float x){ return x >= 0.f ? x : 0.2f*x; }
__device__ __forceinline__ unsigned short f2bf(float f){ unsigned u=__float_as_uint(f); return (unsigned short)((u + 0x7FFFu + ((u>>16)&1u))>>16); }
__device__ __forceinline__ float bf2f(unsigned s){ return __uint_as_float(s<<16); }

// ---------------- K0: prep — element-parallel (+ deg zeroing) ----------------
__global__ __launch_bounds__(256) void prep_kernel(
    const float* __restrict__ Ws, const float* __restrict__ Wd, const float* __restrict__ We,
    const float* __restrict__ as_, const float* __restrict__ ad_, const float* __restrict__ ae_,
    unsigned short* __restrict__ wcmb, unsigned short* __restrict__ webft,
    unsigned short* __restrict__ veb, int* __restrict__ deg, int N)
{
  int tid = blockIdx.x*256 + threadIdx.x;
  int stride = gridDim.x*256;
  for (int idx = tid; idx < NCMB*DINC; idx += stride) {
    int j = idx >> 7, k = idx & 127;
    float w;
    if      (j < 128) w = Ws[j*DINC + k];
    else if (j < 256) w = Wd[(j-128)*DINC + k];
    else if (j < 260) { int h=j-256; float s=0.f; for(int d=0;d<32;++d) s += as_[h*32+d]*Ws[(h*32+d)*DINC+k]; w=s; }
    else if (j < 264) { int h=j-260; float s=0.f; for(int d=0;d<32;++d) s += ad_[h*32+d]*Wd[(h*32+d)*DINC+k]; w=s; }
    else w = 0.f;
    wcmb[idx] = f2bf(w);
  }
  for (int idx = tid; idx < 16*DINC; idx += stride) {   // veb[16][128]: 4 real head rows
    int h = idx >> 7, k = idx & 127;
    float w = 0.f;
    if (h < HH) { float s=0.f; for(int d=0;d<32;++d) s += ae_[h*32+d]*We[(h*32+d)*DINC+k]; w=s; }
    veb[idx] = f2bf(w);
  }
  for (int idx = tid; idx < DINC*OUTC; idx += stride)   // webft[j][k] = We row-major bf16
    webft[idx] = f2bf(We[idx]);
  for (int idx = tid; idx < N; idx += stride) deg[idx] = 0;
}

// ---------------- K1: MFMA node GEMM C[32,272] = X @ [Ws|Wd|vs|vd]^T + fused histogram ----------------
__global__ __launch_bounds__(256) void node_mfma(
    const float* __restrict__ X, const unsigned short* __restrict__ wcmb,
    const int* __restrict__ dst, int* __restrict__ deg,
    unsigned short* __restrict__ hsrcbf, unsigned short* __restrict__ hdstbf,
    float* __restrict__ esrc, float* __restrict__ edst, int N, int E)
{
  int t = threadIdx.x;
  for (long e = (long)blockIdx.x*256 + t; e < E; e += (long)gridDim.x*256)
    atomicAdd(deg + dst[e], 1);

  int lane = t & 63, wv = t >> 6;
  int r16 = lane & 15, g = lane >> 4;
  int n0 = blockIdx.x * 32;
  int ntS = (wv*17) >> 2, ntE = ((wv+1)*17) >> 2;

  #pragma unroll
  for (int mt = 0; mt < 2; ++mt) {
    int arow = n0 + mt*16 + r16; if (arow >= N) arow = N-1;
    bf16x8 a[4];
    #pragma unroll
    for (int kc = 0; kc < 4; ++kc) {
      const float* ap = X + (long)arow*DINC + kc*32 + g*8;
      f32x4 x0 = *(const f32x4*)ap;
      f32x4 x1 = *(const f32x4*)(ap + 4);
      bf16x8 af;
      af[0]=f2bf(x0[0]); af[1]=f2bf(x0[1]); af[2]=f2bf(x0[2]); af[3]=f2bf(x0[3]);
      af[4]=f2bf(x1[0]); af[5]=f2bf(x1[1]); af[6]=f2bf(x1[2]); af[7]=f2bf(x1[3]);
      a[kc] = af;
    }
    for (int nt = ntS; nt < ntE; ++nt) {
      f32x4 acc = (f32x4){0,0,0,0};
      #pragma unroll
      for (int kc = 0; kc < 4; ++kc) {
        bf16x8 bf = *(const bf16x8*)(wcmb + (nt*16 + r16)*DINC + kc*32 + g*8);
        acc = __builtin_amdgcn_mfma_f32_16x16x32_bf16(a[kc], bf, acc, 0, 0, 0);
      }
      int j = nt*16 + r16;   // D: col = lane&15, row = g*4 + r
      #pragma unroll
      for (int r = 0; r < 4; ++r) {
        int n = n0 + mt*16 + g*4 + r;
        if (n >= N) continue;
        float v = acc[r];
        if      (j < 128) hsrcbf[(long)n*OUTC + j] = f2bf(v);
        else if (j < 256) hdstbf[(long)n*OUTC + (j-128)] = f2bf(v);
        else if (j < 260) esrc[(long)n*HH + (j-256)] = v;
        else if (j < 264) edst[(long)n*HH + (j-260)] = v;
      }
    }
  }
}

// ---------------- scan: 3-phase parallel exclusive scan of deg ----------------
__global__ __launch_bounds__(256) void scan1(const int* __restrict__ deg, int* __restrict__ bsum, int N)
{
  __shared__ int sh[256];
  int t = threadIdx.x, blk = blockIdx.x;
  int R = (N + SCAN_B*256 - 1) / (SCAN_B*256);
  int base = (blk*256 + t)*R;
  int s = 0;
  for (int i = 0; i < R; ++i) { int idx = base + i; if (idx < N) s += deg[idx]; }
  sh[t] = s; __syncthreads();
  for (int d = 128; d > 0; d >>= 1) { if (t < d) sh[t] += sh[t+d]; __syncthreads(); }
  if (t == 0) bsum[blk] = sh[0];
}

__global__ __launch_bounds__(64) void scan2(const int* __restrict__ bsum, int* __restrict__ bpre,
                                            int* __restrict__ off, int N)
{
  if (threadIdx.x == 0) {
    int r = 0;
    for (int b = 0; b < SCAN_B; ++b) { bpre[b] = r; r += bsum[b]; }
    off[N] = r;
  }
}

__global__ __launch_bounds__(256) void scan3(const int* __restrict__ deg, const int* __restrict__ bpre,
                                             int* __restrict__ off, int* __restrict__ cursor, int N)
{
  __shared__ int sh[256];
  int t = threadIdx.x, blk = blockIdx.x;
  int R = (N + SCAN_B*256 - 1) / (SCAN_B*256);
  int base = (blk*256 + t)*R;
  int s = 0;
  for (int i = 0; i < R; ++i) { int idx = base + i; if (idx < N) s += deg[idx]; }
  sh[t] = s; __syncthreads();
  for (int d = 1; d < 256; d <<= 1) {
    int v = (t >= d) ? sh[t-d] : 0;
    __syncthreads();
    sh[t] += v;
    __syncthreads();
  }
  int r = bpre[blk] + sh[t] - s;
  for (int i = 0; i < R; ++i) {
    int idx = base + i;
    if (idx < N) { off[idx] = r; cursor[idx] = r; r += deg[idx]; }
  }
}

// ---------------- scatter: 8B CSR records {src, eid} ----------------
__global__ __launch_bounds__(256) void scatter_kernel(
    const int* __restrict__ src, const int* __restrict__ dst,
    int* __restrict__ cursor, unsigned long long* __restrict__ csr, int E)
{
  int e = blockIdx.x*256 + threadIdx.x;
  if (e >= E) return;
  int p = atomicAdd(cursor + dst[e], 1);
  csr[p] = ((unsigned long long)(unsigned)src[e] << 32) | (unsigned)e;
}

// ---------------- K4: FUSED per-node aggregation (R16 body; writes obase, NOT out) ----------------
// Wave = node. Per 16-edge chunk: Phase A gathers Xe rows as MFMA A-frags -> LDS + logit
// MFMA + nu2 -> LDS; Phase B streams the chunk from LDS. Writes Ybf[n][4][128] (bf16) and
// obase[n][128] = h_dst + h_neigh. `out` is written ONLY by proj_mfma (single-writer).
__global__ __launch_bounds__(256) void aggregate_fused(
    const float* __restrict__ Xe, const unsigned short* __restrict__ veb,
    const unsigned* __restrict__ hsrcbfu, const unsigned* __restrict__ hdstbfu,
    const float* __restrict__ esrc, const float* __restrict__ edst,
    const unsigned long long* __restrict__ csr, const int* __restrict__ off,
    unsigned* __restrict__ Ybfu, float* __restrict__ obase, int N)
{
  struct WaveLds {
    unsigned short XeL[16][DINC+8];   // bf16 Xe rows of current chunk (pad 8)
    float S2[16][HH];                 // nu2 per (edge-in-chunk, head)
    int srcL[16];
  };
  __shared__ WaveLds L[4];

  int t = threadIdx.x, wid = t >> 6, lane = t & 63;
  int r16 = lane & 15, g = lane >> 4;
  int n = blockIdx.x*4 + wid;
  bool valid = (n < N);
  int beg = 0, end = 0;
  if (valid) { beg = off[n]; end = off[n+1]; }
  int hl = g;                  // head owned by this lane (cols 2*lane)
  int j0 = 2*lane;
  f32x4 edh4 = valid ? *(const f32x4*)(edst + (long)n*HH) : (f32x4){0,0,0,0};
  float edh  = edh4[hl];
  float edhr = edh4[r16 & 3];

  bf16x8 vebf[4];
  #pragma unroll
  for (int kc = 0; kc < 4; ++kc)
    vebf[kc] = *(const bf16x8*)(veb + r16*DINC + kc*32 + g*8);

  f32x2 acc = {0.f,0.f};
  f32x2 Y0={0,0}, Y1={0,0}, Y2={0,0}, Y3={0,0};
  float s1h = 0.f;
  f32x4 s2v = {0,0,0,0};

  for (int p0 = beg; p0 < end; p0 += 16) {
    int cnt = min(16, end - p0);
    // --- Phase A: csr entries, Xe row gather -> A-frags -> LDS + MFMA logits ---
    long pr = (long)p0 + r16; if (pr >= end) pr = end - 1;
    unsigned long long pk = csr[pr];
    long eid = (long)(unsigned)pk;
    if (lane < 16) L[wid].srcL[lane] = (int)(pk >> 32);

    f32x4 accq = (f32x4){0,0,0,0};
    #pragma unroll
    for (int kc = 0; kc < 4; ++kc) {
      const float* ap = Xe + eid*DINC + kc*32 + g*8;
      f32x4 x0 = *(const f32x4*)ap;
      f32x4 x1 = *(const f32x4*)(ap + 4);
      bf16x8 af;
      af[0]=f2bf(x0[0]); af[1]=f2bf(x0[1]); af[2]=f2bf(x0[2]); af[3]=f2bf(x0[3]);
      af[4]=f2bf(x1[0]); af[5]=f2bf(x1[1]); af[6]=f2bf(x1[2]); af[7]=f2bf(x1[3]);
      *(bf16x8*)&L[wid].XeL[r16][kc*32 + g*8] = af;
      accq = __builtin_amdgcn_mfma_f32_16x16x32_bf16(af, vebf[kc], accq, 0, 0, 0);
    }
    if (r16 < HH) {            // logits D: col r16 = head, row g*4+r = edge-in-chunk
      #pragma unroll
      for (int r = 0; r < 4; ++r) {
        float n2 = ((p0 + g*4 + r) < end) ? __expf(leaky(accq[r] + edhr)) : 0.f;
        L[wid].S2[g*4 + r][r16] = n2;
      }
    }
    asm volatile("s_waitcnt lgkmcnt(0)" ::: "memory");   // wave-local: drain LDS writes
    __builtin_amdgcn_sched_barrier(0);

    // --- Phase B: stream the chunk's edges from LDS ---
    for (int i = 0; i < cnt; ++i) {
      int s_ = L[wid].srcL[i];
      f32x4 nu2 = *(const f32x4*)L[wid].S2[i];
      unsigned xu = *(const unsigned*)&L[wid].XeL[i][j0];
      unsigned hu = hsrcbfu[(long)s_*64 + lane];
      float es_ = esrc[(long)s_*HH + hl];
      float n1 = __expf(leaky(es_ + edh));
      f32x2 xe; xe[0] = bf2f(xu & 0xffffu); xe[1] = bf2f(xu >> 16);
      f32x2 hs; hs[0] = bf2f(hu & 0xffffu); hs[1] = bf2f(hu >> 16);
      s1h += n1; s2v += nu2;
      acc += n1*hs;
      Y0 += nu2[0]*xe; Y1 += nu2[1]*xe; Y2 += nu2[2]*xe; Y3 += nu2[3]*xe;
    }
    asm volatile("" ::: "memory");   // keep next chunk's LDS writes after these reads
  }

  float is1h = (s1h != 0.f) ? 1.f / s1h : 0.f;
  f32x4 is2;
  #pragma unroll
  for (int h=0; h<HH; ++h) is2[h] = (s2v[h] != 0.f) ? 1.f / s2v[h] : 0.f;
  acc *= is1h;
  Y0 *= is2[0]; Y1 *= is2[1]; Y2 *= is2[2]; Y3 *= is2[3];

  if (valid) {
    // Ybf[n][h][k]: lane packs cols (2*lane, 2*lane+1) of each head -> 4 coalesced 256B stores
    unsigned* yp = Ybfu + (long)n*256;
    yp[0*64 + lane] = (unsigned)f2bf(Y0[0]) | ((unsigned)f2bf(Y0[1]) << 16);
    yp[1*64 + lane] = (unsigned)f2bf(Y1[0]) | ((unsigned)f2bf(Y1[1]) << 16);
    yp[2*64 + lane] = (unsigned)f2bf(Y2[0]) | ((unsigned)f2bf(Y2[1]) << 16);
    yp[3*64 + lane] = (unsigned)f2bf(Y3[0]) | ((unsigned)f2bf(Y3[1]) << 16);
    unsigned bu = hdstbfu[(long)n*64 + lane];
    obase[(long)n*OUTC + j0]     = bf2f(bu & 0xffffu) + acc[0];
    obase[(long)n*OUTC + j0 + 1] = bf2f(bu >> 16)     + acc[1];
  }
}

// ---------------- K5: batched projection out[n,j] = obase[n,j] + Y[n, j>>5, :] . We[j, :] ----------------
// Pure overwrite of `out` (single writer). Mirror of node_mfma layout.
__global__ __launch_bounds__(256) void proj_mfma(
    const unsigned short* __restrict__ Ybf,   // [N][4][128] bf16
    const unsigned short* __restrict__ webft, // [128][128] bf16, We row-major
    const float* __restrict__ obase,          // [N][128] f32: h_dst + h_neigh
    float* __restrict__ out, int N)
{
  int t = threadIdx.x, lane = t & 63, wv = t >> 6;
  int r16 = lane & 15, g = lane >> 4;
  int n0 = blockIdx.x * 32;
  int h = wv;                               // head handled by this wave

  #pragma unroll
  for (int mt = 0; mt < 2; ++mt) {
    int arow = n0 + mt*16 + r16; if (arow >= N) arow = N-1;
    bf16x8 a[4];
    #pragma unroll
    for (int kc = 0; kc < 4; ++kc)
      a[kc] = *(const bf16x8*)(Ybf + ((long)arow*4 + h)*DINC + kc*32 + g*8);
    #pragma unroll
    for (int ts = 0; ts < 2; ++ts) {
      int nt = wv*2 + ts;
      f32x4 acc = (f32x4){0,0,0,0};
      #pragma unroll
      for (int kc = 0; kc < 4; ++kc) {
        bf16x8 bw = *(const bf16x8*)(webft + (long)(nt*16 + r16)*DINC + kc*32 + g*8);
        acc = __builtin_amdgcn_mfma_f32_16x16x32_bf16(a[kc], bw, acc, 0, 0, 0);
      }
      int j = nt*16 + r16;   // D: col = lane&15 -> j; row = g*4 + r -> node
      #pragma unroll
      for (int r = 0; r < 4; ++r) {
        int n = n0 + mt*16 + g*4 + r;
        if (n < N) out[(long)n*OUTC + j] = obase[(long)n*OUTC + j] + acc[r];
      }
    }
  }
}

extern "C" void kernel_launch(void* const* d_in, const int* in_sizes, int n_in,
                              void* d_out, int out_size, void* d_ws, size_t ws_size,
                              hipStream_t stream) {
  const float* X   = (const float*)d_in[0];
  const float* Xe  = (const float*)d_in[1];
  const float* Ws  = (const float*)d_in[2];
  const float* Wd  = (const float*)d_in[3];
  const float* We  = (const float*)d_in[4];
  const float* as_ = (const float*)d_in[5];
  const float* ad_ = (const float*)d_in[6];
  const float* ae_ = (const float*)d_in[7];
  const int* src   = (const int*)d_in[8];
  const int* dst   = (const int*)d_in[9];
  int N = in_sizes[0] / DINC;
  int E = in_sizes[8];
  float* out = (float*)d_out;

  char* ws = (char*)d_ws;
  auto align256 = [](size_t x){ return (x + 255) & ~(size_t)255; };
  size_t o_hsrc  = 0;                                        // bf16 [N][128]
  size_t o_hdst  = align256(o_hsrc + (size_t)N*OUTC*2);      // bf16 [N][128]
  size_t o_ybf   = align256(o_hdst + (size_t)N*OUTC*2);      // bf16 [N][4][128]
  size_t o_obase = align256(o_ybf  + (size_t)N*HH*DINC*2);   // f32  [N][128]
  size_t o_esrc  = align256(o_obase+ (size_t)N*OUTC*4);
  size_t o_edst  = align256(o_esrc + (size_t)N*HH*4);
  size_t o_csr   = align256(o_edst + (size_t)N*HH*4);        // u64 [E], CSR order
  size_t o_wcmb  = align256(o_csr  + (size_t)E*8);
  size_t o_webft = align256(o_wcmb + (size_t)NCMB*DINC*2);
  size_t o_veb   = align256(o_webft+ (size_t)DINC*OUTC*2);
  size_t o_deg   = align256(o_veb  + (size_t)16*DINC*2);
  size_t o_off   = align256(o_deg  + (size_t)N*4);
  size_t o_cur   = align256(o_off  + (size_t)(N+4)*4);
  size_t o_bsum  = align256(o_cur  + (size_t)N*4);
  size_t o_bpre  = align256(o_bsum + (size_t)SCAN_B*4);

  unsigned short* hsrcbf = (unsigned short*)(ws + o_hsrc);
  unsigned short* hdstbf = (unsigned short*)(ws + o_hdst);
  unsigned short* ybf    = (unsigned short*)(ws + o_ybf);
  float* obase = (float*)(ws + o_obase);
  float* esrc  = (float*)(ws + o_esrc);
  float* edstp = (float*)(ws + o_edst);
  unsigned long long* csr = (unsigned long long*)(ws + o_csr);
  unsigned short* wcmb  = (unsigned short*)(ws + o_wcmb);
  unsigned short* webft = (unsigned short*)(ws + o_webft);
  unsigned short* veb   = (unsigned short*)(ws + o_veb);
  int* deg     = (int*)(ws + o_deg);
  int* off     = (int*)(ws + o_off);
  int* cursor  = (int*)(ws + o_cur);
  int* bsum    = (int*)(ws + o_bsum);
  int* bpre    = (int*)(ws + o_bpre);

  prep_kernel<<<32, 256, 0, stream>>>(Ws, Wd, We, as_, ad_, ae_, wcmb, webft, veb, deg, N);
  node_mfma<<<(N + 31)/32, 256, 0, stream>>>(X, wcmb, dst, deg, hsrcbf, hdstbf, esrc, edstp, N, E);
  scan1<<<SCAN_B, 256, 0, stream>>>(deg, bsum, N);
  scan2<<<1, 64, 0, stream>>>(bsum, bpre, off, N);
  scan3<<<SCAN_B, 256, 0, stream>>>(deg, bpre, off, cursor, N);
  scatter_kernel<<<(E + 255)/256, 256, 0, stream>>>(src, dst, cursor, csr, E);
  aggregate_fused<<<(N + 3)/4, 256, 0, stream>>>(Xe, veb, (const unsigned*)hsrcbf, (const unsigned*)hdstbf,
                                                 esrc, edstp, csr, off, (unsigned*)ybf, obase, N);
  proj_mfma<<<(N + 31)/32, 256, 0, stream>>>(ybf, webft, obase, out, N);
}